// Round 1
// baseline (1195.652 us; speedup 1.0000x reference)
//
#include <hip/hip_runtime.h>
#include <stdint.h>

#define BB 64      // batch
#define TT 64      // time steps
#define NIN 128
#define NHID 256
#define NOUT 32
#define BPS 4                  // blocks per sample
#define NBLK (BB * BPS)        // 256
#define NTHR 1024
#define ISL 64                 // diff_j rows (i) per block
#define JSL 64                 // j-slice per block for static part

#define SIG_NEU 0.05f
#define SIG_SYN 0.002f

// workspace layout (bytes)
#define CNT_OFF   0
#define CNT_BYTES (TT * BB * 4)                    // 16 KB, memset to 0 each launch
#define PART_OFF  (CNT_OFF + CNT_BYTES)            // float[2][NBLK][NHID]
#define PART_BYTES (2 * NBLK * NHID * 4)           // 512 KB
#define STAT_OFF  (PART_OFF + PART_BYTES)          // float[2][BB][NHID]
#define STAT_BYTES (2 * BB * NHID * 4)             // 128 KB
#define DJ_OFF    (STAT_OFF + STAT_BYTES)          // float[NBLK][ISL*NHID] = 16 MB

#define HID_LIST_SZ ((size_t)BB * TT * NHID)       // 1048576
#define OUT_LIST_SZ ((size_t)BB * TT * NOUT)       // 131072

__device__ __forceinline__ uint32_t rotl32(uint32_t v, int s) {
  return (v << s) | (v >> (32 - s));
}

// JAX threefry2x32 (5 groups of 4 rounds)
__device__ __forceinline__ void tf2x32(uint32_t k0, uint32_t k1, uint32_t x0, uint32_t x1,
                                       uint32_t& o0, uint32_t& o1) {
  const uint32_t k2 = k0 ^ k1 ^ 0x1BD11BDAu;
  x0 += k0; x1 += k1;
  x0 += x1; x1 = rotl32(x1,13); x1 ^= x0;
  x0 += x1; x1 = rotl32(x1,15); x1 ^= x0;
  x0 += x1; x1 = rotl32(x1,26); x1 ^= x0;
  x0 += x1; x1 = rotl32(x1, 6); x1 ^= x0;
  x0 += k1; x1 += k2 + 1u;
  x0 += x1; x1 = rotl32(x1,17); x1 ^= x0;
  x0 += x1; x1 = rotl32(x1,29); x1 ^= x0;
  x0 += x1; x1 = rotl32(x1,16); x1 ^= x0;
  x0 += x1; x1 = rotl32(x1,24); x1 ^= x0;
  x0 += k2; x1 += k0 + 2u;
  x0 += x1; x1 = rotl32(x1,13); x1 ^= x0;
  x0 += x1; x1 = rotl32(x1,15); x1 ^= x0;
  x0 += x1; x1 = rotl32(x1,26); x1 ^= x0;
  x0 += x1; x1 = rotl32(x1, 6); x1 ^= x0;
  x0 += k0; x1 += k1 + 3u;
  x0 += x1; x1 = rotl32(x1,17); x1 ^= x0;
  x0 += x1; x1 = rotl32(x1,29); x1 ^= x0;
  x0 += x1; x1 = rotl32(x1,16); x1 ^= x0;
  x0 += x1; x1 = rotl32(x1,24); x1 ^= x0;
  x0 += k1; x1 += k2 + 4u;
  x0 += x1; x1 = rotl32(x1,13); x1 ^= x0;
  x0 += x1; x1 = rotl32(x1,15); x1 ^= x0;
  x0 += x1; x1 = rotl32(x1,26); x1 ^= x0;
  x0 += x1; x1 = rotl32(x1, 6); x1 ^= x0;
  x0 += k2; x1 += k0 + 5u;
  o0 = x0; o1 = x1;
}

// partitionable random_bits(32) element idx -> N(0,1) exactly as jax.random.normal
__device__ __forceinline__ float tf_normal(uint32_t k0, uint32_t k1, uint32_t idx) {
  uint32_t o0, o1;
  tf2x32(k0, k1, 0u, idx, o0, o1);
  const uint32_t bits = o0 ^ o1;
  const float u = __uint_as_float((bits >> 9) | 0x3f800000u) - 1.0f;  // [0,1)
  float x = fmaf(u, 2.0f, -0.99999994f);                              // [-1+eps, 1)
  x = fmaxf(x, -0.99999994f);
  // XLA ErfInv f32 (Giles)
  const float w = -__logf(fmaf(-x, x, 1.0f));
  float p;
  if (w < 5.0f) {
    const float q = w - 2.5f;
    p = 2.81022636e-08f;
    p = fmaf(p, q, 3.43273939e-07f);
    p = fmaf(p, q, -3.5233877e-06f);
    p = fmaf(p, q, -4.39150654e-06f);
    p = fmaf(p, q, 0.00021858087f);
    p = fmaf(p, q, -0.00125372503f);
    p = fmaf(p, q, -0.00417768164f);
    p = fmaf(p, q, 0.246640727f);
    p = fmaf(p, q, 1.50140941f);
  } else {
    const float q = sqrtf(w) - 3.0f;
    p = -0.000200214257f;
    p = fmaf(p, q, 0.000100950558f);
    p = fmaf(p, q, 0.00134934322f);
    p = fmaf(p, q, -0.00367342844f);
    p = fmaf(p, q, 0.00573950773f);
    p = fmaf(p, q, -0.0076224613f);
    p = fmaf(p, q, 0.00943887047f);
    p = fmaf(p, q, 1.00167406f);
    p = fmaf(p, q, 2.83297682f);
  }
  return 1.41421356f * (p * x);  // sqrt(2)*erfinv
}

__global__ __launch_bounds__(NTHR, 4) void rnn_kernel(
    const float* __restrict__ xin, const float* __restrict__ h0,
    const float* __restrict__ w_in, const float* __restrict__ w_hh,
    const float* __restrict__ b_hh, const float* __restrict__ w_out,
    const float* __restrict__ alpha, const float* __restrict__ beta,
    float* __restrict__ out, char* __restrict__ ws)
{
  __shared__ __align__(16) float whh_s[JSL * NHID];   // 64 KB: this block's W_hh rows
  __shared__ __align__(16) float win_s[JSL * NIN];    // 32 KB: this block's W_in rows
  __shared__ __align__(16) float h_s[NHID];
  __shared__ __align__(16) float a_s[NHID];
  __shared__ __align__(16) float hn_s[NHID];
  __shared__ __align__(16) float xt_s[NIN];
  __shared__ uint32_t keys_s[TT * 4];                 // per-step (k1a,k1b,k2a,k2b)
  __shared__ float pdscr[NTHR];

  const int tid = threadIdx.x;
  const int blk = blockIdx.x;
  const int b   = blk & 63;      // sample; siblings blk = s*64+b land on same XCD (mod-8)
  const int s   = blk >> 6;      // 0..3 slice index

  uint32_t* cnt  = (uint32_t*)(ws + CNT_OFF);
  float*    part = (float*)(ws + PART_OFF);
  float*    stat = (float*)(ws + STAT_OFF);
  float*    dj   = (float*)(ws + DJ_OFF) + (size_t)blk * (ISL * NHID);

  // ---------------- init ----------------
  #pragma unroll
  for (int q = 0; q < 16; ++q) dj[q * NTHR + tid] = 0.0f;            // diff_j starts at 0

  for (int q = 0; q < 16; ++q)
    whh_s[q * NTHR + tid] = w_hh[(size_t)s * JSL * NHID + q * NTHR + tid];
  for (int q = 0; q < 8; ++q)
    win_s[q * NTHR + tid] = w_in[(size_t)s * JSL * NIN + q * NTHR + tid];

  if (tid < TT) {
    uint32_t ka, kb, t0, t1;
    tf2x32(0u, 42u, 0u, (uint32_t)tid, ka, kb);   // keys[t] = split(key(42),64)[t]
    tf2x32(ka, kb, 0u, 0u, t0, t1);               // k1
    keys_s[tid * 4 + 0] = t0; keys_s[tid * 4 + 1] = t1;
    tf2x32(ka, kb, 0u, 1u, t0, t1);               // k2
    keys_s[tid * 4 + 2] = t0; keys_s[tid * 4 + 3] = t1;
  }
  if (tid < NHID) {
    const float hv = h0[b * NHID + tid];
    h_s[tid] = hv;
    a_s[tid] = tanhf(hv);
  }
  const int   j   = tid & 255;
  const float bj  = beta[j];
  const float sbj = SIG_SYN * sqrtf(bj);
  float r_al = 0.f, r_om = 0.f, r_ns = 0.f;
  if (tid < NHID) {
    r_al = alpha[tid];
    r_om = 1.0f - r_al;
    r_ns = SIG_NEU * sqrtf(r_al);
  }
  __syncthreads();

  const int g  = tid >> 8;       // 0..3
  const int i0 = s * ISL;

  for (int t = 0; t < TT; ++t) {
    const int par = t & 1;
    const uint32_t k1a = keys_s[t*4+0], k1b = keys_s[t*4+1];
    const uint32_t k2a = keys_s[t*4+2], k2b = keys_s[t*4+3];

    // load x_t slice, generate neural noise (raw normals)
    if (tid < NIN)  xt_s[tid] = xin[((size_t)b * TT + t) * NIN + tid];
    if (tid < NHID) hn_s[tid] = tf_normal(k1a, k1b, (uint32_t)(b * NHID + tid));

    // ---- phase A main: fused dj_act partial + anti-Hebbian diff_j update ----
    const float aj = a_s[j];
    float pd = 0.0f;
    const uint32_t idx_base = ((uint32_t)b << 16) | ((uint32_t)(i0 + g) << 8) | (uint32_t)j;
    #pragma unroll 4
    for (int r = 0; r < 16; ++r) {
      const int   il = g + 4 * r;
      const float ai = a_s[i0 + il];
      const float n  = tf_normal(k2a, k2b, idx_base + ((uint32_t)(4 * r) << 8));
      const int   off = il * NHID + j;
      const float d  = dj[off];
      pd = fmaf(ai, d, pd);                              // uses OLD diff_j
      dj[off] = fmaf(bj, fmaf(n, sbj, -ai * aj), d);     // dj + beta*(-a_i a_j + sb*n)
    }
    pdscr[tid] = pd;
    __syncthreads();

    // ---- static part: x@W_in^T + act@W_hh^T + bias for this block's j-slice ----
    {
      const int oi  = tid >> 4;          // 0..63 local j
      const int sub = tid & 15;
      const int jj  = s * JSL + oi;
      float acc = 0.0f;
      {
        const float4* wi4 = (const float4*)(win_s + oi * NIN + sub * 8);
        const float4* xv4 = (const float4*)(xt_s + sub * 8);
        #pragma unroll
        for (int q = 0; q < 2; ++q) {
          const float4 wv = wi4[q], xv = xv4[q];
          acc = fmaf(wv.x, xv.x, acc); acc = fmaf(wv.y, xv.y, acc);
          acc = fmaf(wv.z, xv.z, acc); acc = fmaf(wv.w, xv.w, acc);
        }
      }
      {
        const float4* wh4 = (const float4*)(whh_s + oi * NHID + sub * 16);
        const float4* av4 = (const float4*)(a_s + sub * 16);
        #pragma unroll
        for (int q = 0; q < 4; ++q) {
          const float4 wv = wh4[q], av = av4[q];
          acc = fmaf(wv.x, av.x, acc); acc = fmaf(wv.y, av.y, acc);
          acc = fmaf(wv.z, av.z, acc); acc = fmaf(wv.w, av.w, acc);
        }
      }
      acc += __shfl_xor(acc, 8);
      acc += __shfl_xor(acc, 4);
      acc += __shfl_xor(acc, 2);
      acc += __shfl_xor(acc, 1);
      if (sub == 0) {
        const float v = acc + b_hh[jj];
        __hip_atomic_store(&stat[(par * BB + b) * NHID + jj], v,
                           __ATOMIC_RELAXED, __HIP_MEMORY_SCOPE_AGENT);
      }
    }

    // reduce dj_act partial across the 4 thread-groups, publish slot
    if (tid < NHID) {
      const float v = pdscr[tid] + pdscr[tid + 256] + pdscr[tid + 512] + pdscr[tid + 768];
      __hip_atomic_store(&part[(par * NBLK + blk) * NHID + tid], v,
                         __ATOMIC_RELAXED, __HIP_MEMORY_SCOPE_AGENT);
    }

    // ---- 4-block barrier for this (t, sample) ----
    asm volatile("s_waitcnt vmcnt(0)" ::: "memory");  // drain coherent stores (per wave)
    __syncthreads();
    if (tid == 0) {
      uint32_t* c = &cnt[t * BB + b];
      const uint32_t prev = __hip_atomic_fetch_add(c, 1u, __ATOMIC_RELAXED,
                                                   __HIP_MEMORY_SCOPE_AGENT);
      if (prev + 1u < (uint32_t)BPS) {
        while (__hip_atomic_load(c, __ATOMIC_RELAXED, __HIP_MEMORY_SCOPE_AGENT) <
               (uint32_t)BPS)
          __builtin_amdgcn_s_sleep(2);
      }
    }
    __syncthreads();
    asm volatile("" ::: "memory");

    // ---- phase B: combine (redundant per block, bit-identical) ----
    if (tid < NHID) {
      float dj_act =
          __hip_atomic_load(&part[(par * NBLK + 0 * BB + b) * NHID + tid], __ATOMIC_RELAXED, __HIP_MEMORY_SCOPE_AGENT);
      dj_act +=
          __hip_atomic_load(&part[(par * NBLK + 1 * BB + b) * NHID + tid], __ATOMIC_RELAXED, __HIP_MEMORY_SCOPE_AGENT);
      dj_act +=
          __hip_atomic_load(&part[(par * NBLK + 2 * BB + b) * NHID + tid], __ATOMIC_RELAXED, __HIP_MEMORY_SCOPE_AGENT);
      dj_act +=
          __hip_atomic_load(&part[(par * NBLK + 3 * BB + b) * NHID + tid], __ATOMIC_RELAXED, __HIP_MEMORY_SCOPE_AGENT);
      const float st  = __hip_atomic_load(&stat[(par * BB + b) * NHID + tid],
                                          __ATOMIC_RELAXED, __HIP_MEMORY_SCOPE_AGENT);
      const float tmp  = st + dj_act;
      const float hold = h_s[tid];
      const float hnew = fmaf(r_al, tmp, r_om * hold) + hn_s[tid] * r_ns;
      h_s[tid] = hnew;
      a_s[tid] = tanhf(hnew);
      if (s == 0) {
        out[((size_t)b * TT + t) * NHID + tid] = hnew;                       // hidden_list
        if (t == TT - 1)
          out[HID_LIST_SZ + OUT_LIST_SZ + (size_t)b * NHID + tid] = hnew;    // final hidden
      }
    }
    __syncthreads();

    // ---- output projection (only s==0 writes) ----
    if (s == 0 && tid < NOUT * 16) {
      const int o   = tid >> 4;
      const int sub = tid & 15;
      float acc = 0.0f;
      const float4* wo4 = (const float4*)(w_out + o * NHID + sub * 16);
      const float4* hh4 = (const float4*)(h_s + sub * 16);
      #pragma unroll
      for (int q = 0; q < 4; ++q) {
        const float4 wv = wo4[q], hv = hh4[q];
        acc = fmaf(wv.x, hv.x, acc); acc = fmaf(wv.y, hv.y, acc);
        acc = fmaf(wv.z, hv.z, acc); acc = fmaf(wv.w, hv.w, acc);
      }
      acc += __shfl_xor(acc, 8);
      acc += __shfl_xor(acc, 4);
      acc += __shfl_xor(acc, 2);
      acc += __shfl_xor(acc, 1);
      if (sub == 0)
        out[HID_LIST_SZ + ((size_t)b * TT + t) * NOUT + o] = 20.0f * tanhf(acc);
    }
    __syncthreads();  // protect xt_s/hn_s/pdscr for next iteration
  }
}

extern "C" void kernel_launch(void* const* d_in, const int* in_sizes, int n_in,
                              void* d_out, int out_size, void* d_ws, size_t ws_size,
                              hipStream_t stream) {
  (void)in_sizes; (void)n_in; (void)out_size; (void)ws_size;
  const float* x     = (const float*)d_in[0];
  const float* h0    = (const float*)d_in[1];
  // d_in[2] = length (always 64)
  const float* w_in  = (const float*)d_in[3];
  const float* w_hh  = (const float*)d_in[4];
  const float* b_hh  = (const float*)d_in[5];
  const float* w_out = (const float*)d_in[6];
  const float* alpha = (const float*)d_in[7];
  const float* beta  = (const float*)d_in[8];
  float* out = (float*)d_out;

  hipMemsetAsync((char*)d_ws + CNT_OFF, 0, CNT_BYTES, stream);  // arrive counters
  rnn_kernel<<<dim3(NBLK), dim3(NTHR), 0, stream>>>(
      x, h0, w_in, w_hh, b_hh, w_out, alpha, beta, out, (char*)d_ws);
}

// Round 2
// 1136.502 us; speedup vs baseline: 1.0520x; 1.0520x over previous
//
#include <hip/hip_runtime.h>
#include <stdint.h>

#define BB 64      // batch
#define TT 64      // time steps
#define NIN 128
#define NHID 256
#define NOUT 32
#define BPS 8                  // blocks per sample (j-sliced)
#define NBLK (BB * BPS)        // 512
#define NTHR 1024
#define JS 32                  // j-columns per block

#define SIG_NEU 0.05f
#define SIG_SYN 0.002f

// workspace layout (bytes)
#define CNT_OFF   0
#define CNT_BYTES (TT * BB * 4)                    // 16 KB, memset to 0 each launch
#define HPUB_OFF  (CNT_OFF + CNT_BYTES)            // float[2][BB][NHID] = 128 KB

#define HID_LIST_SZ ((size_t)BB * TT * NHID)       // 1048576
#define OUT_LIST_SZ ((size_t)BB * TT * NOUT)       // 131072

__device__ __forceinline__ uint32_t rotl32(uint32_t v, int s) {
  return (v << s) | (v >> (32 - s));
}

// JAX threefry2x32 (5 groups of 4 rounds)
__device__ __forceinline__ void tf2x32(uint32_t k0, uint32_t k1, uint32_t x0, uint32_t x1,
                                       uint32_t& o0, uint32_t& o1) {
  const uint32_t k2 = k0 ^ k1 ^ 0x1BD11BDAu;
  x0 += k0; x1 += k1;
  x0 += x1; x1 = rotl32(x1,13); x1 ^= x0;
  x0 += x1; x1 = rotl32(x1,15); x1 ^= x0;
  x0 += x1; x1 = rotl32(x1,26); x1 ^= x0;
  x0 += x1; x1 = rotl32(x1, 6); x1 ^= x0;
  x0 += k1; x1 += k2 + 1u;
  x0 += x1; x1 = rotl32(x1,17); x1 ^= x0;
  x0 += x1; x1 = rotl32(x1,29); x1 ^= x0;
  x0 += x1; x1 = rotl32(x1,16); x1 ^= x0;
  x0 += x1; x1 = rotl32(x1,24); x1 ^= x0;
  x0 += k2; x1 += k0 + 2u;
  x0 += x1; x1 = rotl32(x1,13); x1 ^= x0;
  x0 += x1; x1 = rotl32(x1,15); x1 ^= x0;
  x0 += x1; x1 = rotl32(x1,26); x1 ^= x0;
  x0 += x1; x1 = rotl32(x1, 6); x1 ^= x0;
  x0 += k0; x1 += k1 + 3u;
  x0 += x1; x1 = rotl32(x1,17); x1 ^= x0;
  x0 += x1; x1 = rotl32(x1,29); x1 ^= x0;
  x0 += x1; x1 = rotl32(x1,16); x1 ^= x0;
  x0 += x1; x1 = rotl32(x1,24); x1 ^= x0;
  x0 += k1; x1 += k2 + 4u;
  x0 += x1; x1 = rotl32(x1,13); x1 ^= x0;
  x0 += x1; x1 = rotl32(x1,15); x1 ^= x0;
  x0 += x1; x1 = rotl32(x1,26); x1 ^= x0;
  x0 += x1; x1 = rotl32(x1, 6); x1 ^= x0;
  x0 += k2; x1 += k0 + 5u;
  o0 = x0; o1 = x1;
}

// partitionable random_bits(32) element idx -> N(0,1) exactly as jax.random.normal
__device__ __forceinline__ float tf_normal(uint32_t k0, uint32_t k1, uint32_t idx) {
  uint32_t o0, o1;
  tf2x32(k0, k1, 0u, idx, o0, o1);
  const uint32_t bits = o0 ^ o1;
  const float u = __uint_as_float((bits >> 9) | 0x3f800000u) - 1.0f;  // [0,1)
  float x = fmaf(u, 2.0f, -0.99999994f);                              // [-1+eps, 1)
  x = fmaxf(x, -0.99999994f);
  // XLA ErfInv f32 (Giles)
  const float w = -__logf(fmaf(-x, x, 1.0f));
  float p;
  if (w < 5.0f) {
    const float q = w - 2.5f;
    p = 2.81022636e-08f;
    p = fmaf(p, q, 3.43273939e-07f);
    p = fmaf(p, q, -3.5233877e-06f);
    p = fmaf(p, q, -4.39150654e-06f);
    p = fmaf(p, q, 0.00021858087f);
    p = fmaf(p, q, -0.00125372503f);
    p = fmaf(p, q, -0.00417768164f);
    p = fmaf(p, q, 0.246640727f);
    p = fmaf(p, q, 1.50140941f);
  } else {
    const float q = sqrtf(w) - 3.0f;
    p = -0.000200214257f;
    p = fmaf(p, q, 0.000100950558f);
    p = fmaf(p, q, 0.00134934322f);
    p = fmaf(p, q, -0.00367342844f);
    p = fmaf(p, q, 0.00573950773f);
    p = fmaf(p, q, -0.0076224613f);
    p = fmaf(p, q, 0.00943887047f);
    p = fmaf(p, q, 1.00167406f);
    p = fmaf(p, q, 2.83297682f);
  }
  return 1.41421356f * (p * x);  // sqrt(2)*erfinv
}

__global__ __launch_bounds__(NTHR, 8) void rnn_kernel(
    const float* __restrict__ xin, const float* __restrict__ h0,
    const float* __restrict__ w_in, const float* __restrict__ w_hh,
    const float* __restrict__ b_hh, const float* __restrict__ w_out,
    const float* __restrict__ alpha, const float* __restrict__ beta,
    float* __restrict__ out, char* __restrict__ ws)
{
  __shared__ __align__(16) float dj_s[NHID * JS];   // [i 256][jl 32] = 32 KB, block-local
  __shared__ __align__(16) float4 pdwave[16][8];    // per-wave partial dj_act, 2 KB
  __shared__ __align__(16) float h_s[NHID];
  __shared__ __align__(16) float a_s[NHID];
  __shared__ __align__(16) float xt_s[NIN];
  __shared__ float stat_s[JS];
  __shared__ float djact_s[JS];
  __shared__ float hn_s[JS];
  __shared__ uint32_t keys_s[TT * 4];

  const int tid = threadIdx.x;
  const int blk = blockIdx.x;
  const int b   = blk & 63;      // sample; siblings blk = s*64+b share blk%8 -> same XCD class
  const int s   = blk >> 6;      // 0..7 j-slice index

  uint32_t* cnt  = (uint32_t*)(ws + CNT_OFF);
  float*    hpub = (float*)(ws + HPUB_OFF);

  // ---------------- init ----------------
  #pragma unroll
  for (int q = 0; q < 8; ++q) dj_s[q * NTHR + tid] = 0.0f;

  if (tid < TT) {
    uint32_t ka, kb, t0, t1;
    tf2x32(0u, 42u, 0u, (uint32_t)tid, ka, kb);   // keys[t] = split(key(42),64)[t]
    tf2x32(ka, kb, 0u, 0u, t0, t1);               // k1 (neural)
    keys_s[tid * 4 + 0] = t0; keys_s[tid * 4 + 1] = t1;
    tf2x32(ka, kb, 0u, 1u, t0, t1);               // k2 (synaptic)
    keys_s[tid * 4 + 2] = t0; keys_s[tid * 4 + 3] = t1;
  }
  if (tid < NHID) {
    const float hv = h0[b * NHID + tid];
    h_s[tid] = hv;
    a_s[tid] = tanhf(hv);
  }

  // dj-pass mapping: thread owns j-quad jq (4 consecutive j) x i-rows {it, it+128}
  const int jq  = tid & 7;
  const int it  = tid >> 3;          // 0..127
  const int jg0 = s * JS + jq * 4;   // global j of quad base
  const float4 bj4 = *(const float4*)(beta + jg0);
  const float4 sb4 = make_float4(SIG_SYN * sqrtf(bj4.x), SIG_SYN * sqrtf(bj4.y),
                                 SIG_SYN * sqrtf(bj4.z), SIG_SYN * sqrtf(bj4.w));

  // h-combine consts (tid<32 only)
  float r_al = 0.f, r_om = 0.f, r_ns = 0.f;
  if (tid < JS) {
    r_al = alpha[s * JS + tid];
    r_om = 1.0f - r_al;
    r_ns = SIG_NEU * sqrtf(r_al);
  }

  // static-GEMV mapping (tid<512): 32 rows x 16 lanes each
  const int jl   = tid >> 4;         // 0..63 (valid <32 when tid<512)
  const int sub  = tid & 15;
  const int jrow = s * JS + (jl & 31);
  const float4* wi = (const float4*)(w_in + jrow * NIN + sub * 8);
  const float4* wh = (const float4*)(w_hh + (size_t)jrow * NHID + sub * 16);
  const float bias = (tid < 512) ? b_hh[jrow] : 0.0f;

  // output-projection mapping (tid<64): this block computes outputs o = s*4 .. s*4+3
  const int oo = s * 4 + ((tid >> 4) & 3);
  const float4* wo = (const float4*)(w_out + oo * NHID + sub * 16);

  __syncthreads();

  for (int t = 0; t < TT; ++t) {
    const int par = t & 1;
    const uint32_t k1a = keys_s[t*4+0], k1b = keys_s[t*4+1];
    const uint32_t k2a = keys_s[t*4+2], k2b = keys_s[t*4+3];

    if (tid < NIN) xt_s[tid] = xin[((size_t)b * TT + t) * NIN + tid];

    // ---- A1: dj read/update + partial dj_act (all threads) ----
    const float4 aj4 = *(const float4*)(a_s + jg0);
    float4 pd = make_float4(0.f, 0.f, 0.f, 0.f);
    #pragma unroll
    for (int r = 0; r < 2; ++r) {
      const int i = it + 128 * r;
      const float ai = a_s[i];
      float4* dp = (float4*)(dj_s + i * JS + jq * 4);
      float4 d = *dp;
      const uint32_t idx0 = ((uint32_t)b << 16) | ((uint32_t)i << 8) | (uint32_t)jg0;
      const float n0 = tf_normal(k2a, k2b, idx0 + 0u);
      const float n1 = tf_normal(k2a, k2b, idx0 + 1u);
      const float n2 = tf_normal(k2a, k2b, idx0 + 2u);
      const float n3 = tf_normal(k2a, k2b, idx0 + 3u);
      pd.x = fmaf(ai, d.x, pd.x);
      pd.y = fmaf(ai, d.y, pd.y);
      pd.z = fmaf(ai, d.z, pd.z);
      pd.w = fmaf(ai, d.w, pd.w);
      d.x = fmaf(bj4.x, fmaf(n0, sb4.x, -ai * aj4.x), d.x);
      d.y = fmaf(bj4.y, fmaf(n1, sb4.y, -ai * aj4.y), d.y);
      d.z = fmaf(bj4.z, fmaf(n2, sb4.z, -ai * aj4.z), d.z);
      d.w = fmaf(bj4.w, fmaf(n3, sb4.w, -ai * aj4.w), d.w);
      *dp = d;
    }
    // in-wave reduce pd over the 8 it-values sharing this jq (lanes xor 8,16,32)
    pd.x += __shfl_xor(pd.x, 8);  pd.y += __shfl_xor(pd.y, 8);
    pd.z += __shfl_xor(pd.z, 8);  pd.w += __shfl_xor(pd.w, 8);
    pd.x += __shfl_xor(pd.x, 16); pd.y += __shfl_xor(pd.y, 16);
    pd.z += __shfl_xor(pd.z, 16); pd.w += __shfl_xor(pd.w, 16);
    pd.x += __shfl_xor(pd.x, 32); pd.y += __shfl_xor(pd.y, 32);
    pd.z += __shfl_xor(pd.z, 32); pd.w += __shfl_xor(pd.w, 32);
    if ((tid & 63) < 8) pdwave[tid >> 6][jq] = pd;
    __syncthreads();

    // ---- A2: static GEMV (waves 0-7) | pdwave reduce + neural noise (wave 8) ----
    if (tid < 512) {
      float acc = 0.0f;
      const float4 xa = *(const float4*)(xt_s + sub * 8);
      const float4 xbv = *(const float4*)(xt_s + sub * 8 + 4);
      const float4 w0 = wi[0], w1 = wi[1];
      acc = fmaf(w0.x, xa.x, acc);  acc = fmaf(w0.y, xa.y, acc);
      acc = fmaf(w0.z, xa.z, acc);  acc = fmaf(w0.w, xa.w, acc);
      acc = fmaf(w1.x, xbv.x, acc); acc = fmaf(w1.y, xbv.y, acc);
      acc = fmaf(w1.z, xbv.z, acc); acc = fmaf(w1.w, xbv.w, acc);
      #pragma unroll
      for (int q = 0; q < 4; ++q) {
        const float4 wv = wh[q];
        const float4 av = *(const float4*)(a_s + sub * 16 + q * 4);
        acc = fmaf(wv.x, av.x, acc); acc = fmaf(wv.y, av.y, acc);
        acc = fmaf(wv.z, av.z, acc); acc = fmaf(wv.w, av.w, acc);
      }
      acc += __shfl_xor(acc, 8);
      acc += __shfl_xor(acc, 4);
      acc += __shfl_xor(acc, 2);
      acc += __shfl_xor(acc, 1);
      if (sub == 0) stat_s[jl] = acc + bias;
    } else if (tid < 544) {
      const int k = tid & 31;          // jl = k; component c = k&3, quad q = k>>2
      const int c = k & 3, q = k >> 2;
      float sum = 0.f;
      #pragma unroll
      for (int wv = 0; wv < 16; ++wv)
        sum += ((const float*)&pdwave[wv][q])[c];
      djact_s[k] = sum;
    } else if (tid < 576) {
      const int k = tid & 31;
      hn_s[k] = tf_normal(k1a, k1b, (uint32_t)(b * NHID + s * JS + k));
    }
    __syncthreads();

    // ---- A3: h update for own 32 j, publish ----
    if (tid < JS) {
      const int jg = s * JS + tid;
      const float tmp  = stat_s[tid] + djact_s[tid];
      const float hnew = fmaf(r_al, tmp, r_om * h_s[jg]) + hn_s[tid] * r_ns;
      out[((size_t)b * TT + t) * NHID + jg] = hnew;                        // hidden_list
      if (t == TT - 1)
        out[HID_LIST_SZ + OUT_LIST_SZ + (size_t)b * NHID + jg] = hnew;     // final hidden
      __hip_atomic_store(&hpub[(par * BB + b) * NHID + jg], hnew,
                         __ATOMIC_RELAXED, __HIP_MEMORY_SCOPE_AGENT);
    }

    // ---- 8-block barrier for this (t, sample) ----
    asm volatile("s_waitcnt vmcnt(0)" ::: "memory");
    __syncthreads();
    if (tid == 0) {
      uint32_t* c = &cnt[t * BB + b];
      const uint32_t prev = __hip_atomic_fetch_add(c, 1u, __ATOMIC_RELAXED,
                                                   __HIP_MEMORY_SCOPE_AGENT);
      if (prev + 1u < (uint32_t)BPS) {
        while (__hip_atomic_load(c, __ATOMIC_RELAXED, __HIP_MEMORY_SCOPE_AGENT) <
               (uint32_t)BPS)
          __builtin_amdgcn_s_sleep(2);
      }
    }
    __syncthreads();
    asm volatile("" ::: "memory");

    // ---- B: pull full h, refresh act ----
    if (tid < NHID) {
      const float hv = __hip_atomic_load(&hpub[(par * BB + b) * NHID + tid],
                                         __ATOMIC_RELAXED, __HIP_MEMORY_SCOPE_AGENT);
      h_s[tid] = hv;
      a_s[tid] = tanhf(hv);
    }
    __syncthreads();

    // ---- output projection: 4 outputs per block ----
    if (tid < 64) {
      float acc = 0.0f;
      #pragma unroll
      for (int q = 0; q < 4; ++q) {
        const float4 wv = wo[q];
        const float4 hv = *(const float4*)(h_s + sub * 16 + q * 4);
        acc = fmaf(wv.x, hv.x, acc); acc = fmaf(wv.y, hv.y, acc);
        acc = fmaf(wv.z, hv.z, acc); acc = fmaf(wv.w, hv.w, acc);
      }
      acc += __shfl_xor(acc, 8);
      acc += __shfl_xor(acc, 4);
      acc += __shfl_xor(acc, 2);
      acc += __shfl_xor(acc, 1);
      if (sub == 0)
        out[HID_LIST_SZ + ((size_t)b * TT + t) * NOUT + oo] = 20.0f * tanhf(acc);
    }
  }
}

extern "C" void kernel_launch(void* const* d_in, const int* in_sizes, int n_in,
                              void* d_out, int out_size, void* d_ws, size_t ws_size,
                              hipStream_t stream) {
  (void)in_sizes; (void)n_in; (void)out_size; (void)ws_size;
  const float* x     = (const float*)d_in[0];
  const float* h0    = (const float*)d_in[1];
  // d_in[2] = length (always 64)
  const float* w_in  = (const float*)d_in[3];
  const float* w_hh  = (const float*)d_in[4];
  const float* b_hh  = (const float*)d_in[5];
  const float* w_out = (const float*)d_in[6];
  const float* alpha = (const float*)d_in[7];
  const float* beta  = (const float*)d_in[8];
  float* out = (float*)d_out;

  hipMemsetAsync((char*)d_ws + CNT_OFF, 0, CNT_BYTES, stream);  // arrive counters
  rnn_kernel<<<dim3(NBLK), dim3(NTHR), 0, stream>>>(
      x, h0, w_in, w_hh, b_hh, w_out, alpha, beta, out, (char*)d_ws);
}

// Round 3
// 1058.289 us; speedup vs baseline: 1.1298x; 1.0739x over previous
//
#include <hip/hip_runtime.h>
#include <stdint.h>

#define BB 64      // batch
#define TT 64      // time steps
#define NIN 128
#define NHID 256
#define NOUT 32
#define BPS 8                  // blocks per sample (j-sliced)
#define NBLK (BB * BPS)        // 512
#define NTHR 1024
#define JS 32                  // j-columns per block

#define SIG_NEU 0.05f
#define SIG_SYN 0.002f

// workspace layout (bytes)
#define CNT_STRIDE 32                               // 128B per counter: no line sharing
#define CNT_OFF   0
#define CNT_BYTES (TT * BB * CNT_STRIDE * 4)        // 512 KB, memset to 0 each launch
#define HPUB_OFF  (CNT_OFF + CNT_BYTES)             // float[2][BB][NHID] = 128 KB

#define HID_LIST_SZ ((size_t)BB * TT * NHID)        // 1048576
#define OUT_LIST_SZ ((size_t)BB * TT * NOUT)        // 131072

__device__ __forceinline__ uint32_t rotl32(uint32_t v, int s) {
  return (v << s) | (v >> (32 - s));
}

// JAX threefry2x32 (5 groups of 4 rounds)
__device__ __forceinline__ void tf2x32(uint32_t k0, uint32_t k1, uint32_t x0, uint32_t x1,
                                       uint32_t& o0, uint32_t& o1) {
  const uint32_t k2 = k0 ^ k1 ^ 0x1BD11BDAu;
  x0 += k0; x1 += k1;
  x0 += x1; x1 = rotl32(x1,13); x1 ^= x0;
  x0 += x1; x1 = rotl32(x1,15); x1 ^= x0;
  x0 += x1; x1 = rotl32(x1,26); x1 ^= x0;
  x0 += x1; x1 = rotl32(x1, 6); x1 ^= x0;
  x0 += k1; x1 += k2 + 1u;
  x0 += x1; x1 = rotl32(x1,17); x1 ^= x0;
  x0 += x1; x1 = rotl32(x1,29); x1 ^= x0;
  x0 += x1; x1 = rotl32(x1,16); x1 ^= x0;
  x0 += x1; x1 = rotl32(x1,24); x1 ^= x0;
  x0 += k2; x1 += k0 + 2u;
  x0 += x1; x1 = rotl32(x1,13); x1 ^= x0;
  x0 += x1; x1 = rotl32(x1,15); x1 ^= x0;
  x0 += x1; x1 = rotl32(x1,26); x1 ^= x0;
  x0 += x1; x1 = rotl32(x1, 6); x1 ^= x0;
  x0 += k0; x1 += k1 + 3u;
  x0 += x1; x1 = rotl32(x1,17); x1 ^= x0;
  x0 += x1; x1 = rotl32(x1,29); x1 ^= x0;
  x0 += x1; x1 = rotl32(x1,16); x1 ^= x0;
  x0 += x1; x1 = rotl32(x1,24); x1 ^= x0;
  x0 += k1; x1 += k2 + 4u;
  x0 += x1; x1 = rotl32(x1,13); x1 ^= x0;
  x0 += x1; x1 = rotl32(x1,15); x1 ^= x0;
  x0 += x1; x1 = rotl32(x1,26); x1 ^= x0;
  x0 += x1; x1 = rotl32(x1, 6); x1 ^= x0;
  x0 += k2; x1 += k0 + 5u;
  o0 = x0; o1 = x1;
}

// partitionable random_bits(32) element idx -> N(0,1) exactly as jax.random.normal
__device__ __forceinline__ float tf_normal(uint32_t k0, uint32_t k1, uint32_t idx) {
  uint32_t o0, o1;
  tf2x32(k0, k1, 0u, idx, o0, o1);
  const uint32_t bits = o0 ^ o1;
  const float u = __uint_as_float((bits >> 9) | 0x3f800000u) - 1.0f;  // [0,1)
  float x = fmaf(u, 2.0f, -0.99999994f);                              // [-1+eps, 1)
  x = fmaxf(x, -0.99999994f);
  // XLA ErfInv f32 (Giles)
  const float w = -__logf(fmaf(-x, x, 1.0f));
  float p;
  if (w < 5.0f) {
    const float q = w - 2.5f;
    p = 2.81022636e-08f;
    p = fmaf(p, q, 3.43273939e-07f);
    p = fmaf(p, q, -3.5233877e-06f);
    p = fmaf(p, q, -4.39150654e-06f);
    p = fmaf(p, q, 0.00021858087f);
    p = fmaf(p, q, -0.00125372503f);
    p = fmaf(p, q, -0.00417768164f);
    p = fmaf(p, q, 0.246640727f);
    p = fmaf(p, q, 1.50140941f);
  } else {
    const float q = sqrtf(w) - 3.0f;
    p = -0.000200214257f;
    p = fmaf(p, q, 0.000100950558f);
    p = fmaf(p, q, 0.00134934322f);
    p = fmaf(p, q, -0.00367342844f);
    p = fmaf(p, q, 0.00573950773f);
    p = fmaf(p, q, -0.0076224613f);
    p = fmaf(p, q, 0.00943887047f);
    p = fmaf(p, q, 1.00167406f);
    p = fmaf(p, q, 2.83297682f);
  }
  return 1.41421356f * (p * x);  // sqrt(2)*erfinv
}

__global__ __launch_bounds__(NTHR, 8) void rnn_kernel(
    const float* __restrict__ xin, const float* __restrict__ h0,
    const float* __restrict__ w_in, const float* __restrict__ w_hh,
    const float* __restrict__ b_hh, const float* __restrict__ w_out,
    const float* __restrict__ alpha, const float* __restrict__ beta,
    float* __restrict__ out, char* __restrict__ ws)
{
  __shared__ __align__(16) float h_s[NHID];
  __shared__ __align__(16) float a_s[NHID];
  __shared__ __align__(16) float xt_s[NIN];
  __shared__ float stat_s[JS];
  __shared__ float djact_s[JS];
  __shared__ uint32_t keys_s[TT * 4];

  const int tid = threadIdx.x;
  const int blk = blockIdx.x;
  const int b   = blk & 63;      // sample; siblings share blk%8 -> same XCD class
  const int s   = blk >> 6;      // 0..7 j-slice index

  uint32_t* cnt  = (uint32_t*)(ws + CNT_OFF);
  float*    hpub = (float*)(ws + HPUB_OFF);

  // ---------------- init ----------------
  if (tid < TT) {
    uint32_t ka, kb, t0, t1;
    tf2x32(0u, 42u, 0u, (uint32_t)tid, ka, kb);   // keys[t] = split(key(42),64)[t]
    tf2x32(ka, kb, 0u, 0u, t0, t1);               // k1 (neural)
    keys_s[tid * 4 + 0] = t0; keys_s[tid * 4 + 1] = t1;
    tf2x32(ka, kb, 0u, 1u, t0, t1);               // k2 (synaptic)
    keys_s[tid * 4 + 2] = t0; keys_s[tid * 4 + 3] = t1;
  }
  if (tid < NHID) {
    const float hv = h0[b * NHID + tid];
    h_s[tid] = hv;
    a_s[tid] = tanhf(hv);
  }

  // dj mapping: thread owns column j = jl (global jg), rows i = u + 32r, r=0..7
  const int u  = tid & 31;
  const int jl = tid >> 5;           // 0..31
  const int jg = s * JS + jl;
  const float bj  = beta[jg];
  const float sbj = SIG_SYN * sqrtf(bj);
  const uint32_t idxb = ((uint32_t)b << 16) | ((uint32_t)u << 8) | (uint32_t)jg;

  // h-update consts (tid<32)
  float r_al = 0.f, r_om = 0.f, r_ns = 0.f;
  uint32_t hnidx = 0;
  if (tid < JS) {
    r_al = alpha[s * JS + tid];
    r_om = 1.0f - r_al;
    r_ns = SIG_NEU * sqrtf(r_al);
    hnidx = (uint32_t)(b * NHID + s * JS + tid);
  }

  // static-GEMV mapping (tid<512): 32 rows x 16 lanes each
  const int row  = (tid >> 4) & 31;
  const int sub  = tid & 15;
  const int jrow = s * JS + row;
  const float4* wi = (const float4*)(w_in + jrow * NIN + sub * 8);
  const float4* wh = (const float4*)(w_hh + (size_t)jrow * NHID + sub * 16);
  const float bias = b_hh[jrow];

  // output-projection mapping (tid 512..575): outputs o = s*4 .. s*4+3
  const int oo = s * 4 + ((tid >> 4) & 3);
  const float4* wo = (const float4*)(w_out + oo * NHID + sub * 16);

  float d[8];
  #pragma unroll
  for (int r = 0; r < 8; ++r) d[r] = 0.0f;
  float n[8];
  float hn = 0.0f;

  __syncthreads();

  // -------- prologue: RNG for t=0, x_0 --------
  {
    const uint32_t k2a = __builtin_amdgcn_readfirstlane(keys_s[2]);
    const uint32_t k2b = __builtin_amdgcn_readfirstlane(keys_s[3]);
    #pragma unroll
    for (int r = 0; r < 8; ++r)
      n[r] = tf_normal(k2a, k2b, idxb + (uint32_t)(r * 8192));
    if (tid < JS) {
      const uint32_t k1a = __builtin_amdgcn_readfirstlane(keys_s[0]);
      const uint32_t k1b = __builtin_amdgcn_readfirstlane(keys_s[1]);
      hn = tf_normal(k1a, k1b, hnidx);
    }
    if (tid < NIN) xt_s[tid] = xin[((size_t)b * TT) * NIN + tid];
  }
  __syncthreads();

  for (int t = 0; t < TT; ++t) {
    const int par = t & 1;

    // ---- P1: dj update + pd (all) | static GEMV (waves 0-7) | outproj t-1 (wave 8) ----
    const float aj = a_s[jg];
    float pd = 0.0f;
    #pragma unroll
    for (int r = 0; r < 8; ++r) {
      const float ai = a_s[u + 32 * r];
      pd = fmaf(ai, d[r], pd);                         // uses OLD dj
      d[r] = fmaf(bj, fmaf(n[r], sbj, -ai * aj), d[r]);
    }
    pd += __shfl_xor(pd, 1);
    pd += __shfl_xor(pd, 2);
    pd += __shfl_xor(pd, 4);
    pd += __shfl_xor(pd, 8);
    pd += __shfl_xor(pd, 16);
    if (u == 0) djact_s[jl] = pd;

    if (tid < 512) {
      float acc = 0.0f;
      const float4 xa = *(const float4*)(xt_s + sub * 8);
      const float4 xb = *(const float4*)(xt_s + sub * 8 + 4);
      const float4 w0 = wi[0], w1 = wi[1];
      acc = fmaf(w0.x, xa.x, acc); acc = fmaf(w0.y, xa.y, acc);
      acc = fmaf(w0.z, xa.z, acc); acc = fmaf(w0.w, xa.w, acc);
      acc = fmaf(w1.x, xb.x, acc); acc = fmaf(w1.y, xb.y, acc);
      acc = fmaf(w1.z, xb.z, acc); acc = fmaf(w1.w, xb.w, acc);
      #pragma unroll
      for (int q = 0; q < 4; ++q) {
        const float4 wv = wh[q];
        const float4 av = *(const float4*)(a_s + sub * 16 + q * 4);
        acc = fmaf(wv.x, av.x, acc); acc = fmaf(wv.y, av.y, acc);
        acc = fmaf(wv.z, av.z, acc); acc = fmaf(wv.w, av.w, acc);
      }
      acc += __shfl_xor(acc, 8);
      acc += __shfl_xor(acc, 4);
      acc += __shfl_xor(acc, 2);
      acc += __shfl_xor(acc, 1);
      if (sub == 0) stat_s[row] = acc + bias;
    } else if (tid < 576 && t > 0) {
      float acc = 0.0f;
      #pragma unroll
      for (int q = 0; q < 4; ++q) {
        const float4 wv = wo[q];
        const float4 hv = *(const float4*)(h_s + sub * 16 + q * 4);
        acc = fmaf(wv.x, hv.x, acc); acc = fmaf(wv.y, hv.y, acc);
        acc = fmaf(wv.z, hv.z, acc); acc = fmaf(wv.w, hv.w, acc);
      }
      acc += __shfl_xor(acc, 8);
      acc += __shfl_xor(acc, 4);
      acc += __shfl_xor(acc, 2);
      acc += __shfl_xor(acc, 1);
      if (sub == 0)
        out[HID_LIST_SZ + ((size_t)b * TT + (t - 1)) * NOUT + oo] = 20.0f * tanhf(acc);
    }
    __syncthreads();

    // ---- P2: h-update + barrier arrive, then RNG for t+1 (hides barrier) ----
    if (tid < JS) {
      const float tmp  = stat_s[tid] + djact_s[tid];
      const float hnew = fmaf(r_al, tmp, r_om * h_s[s * JS + tid]) + hn * r_ns;
      __hip_atomic_store(&hpub[(par * BB + b) * NHID + s * JS + tid], hnew,
                         __ATOMIC_RELAXED, __HIP_MEMORY_SCOPE_AGENT);
    }
    if (tid == 0) {
      asm volatile("s_waitcnt vmcnt(0)" ::: "memory");   // drain only the hpub store
      __hip_atomic_fetch_add(&cnt[((size_t)t * BB + b) * CNT_STRIDE], 1u,
                             __ATOMIC_RELAXED, __HIP_MEMORY_SCOPE_AGENT);
    }
    {
      const int tn = (t + 1) & 63;
      const uint32_t k2a = __builtin_amdgcn_readfirstlane(keys_s[tn * 4 + 2]);
      const uint32_t k2b = __builtin_amdgcn_readfirstlane(keys_s[tn * 4 + 3]);
      #pragma unroll
      for (int r = 0; r < 8; ++r)
        n[r] = tf_normal(k2a, k2b, idxb + (uint32_t)(r * 8192));
      if (tid < JS) {
        const uint32_t k1a = __builtin_amdgcn_readfirstlane(keys_s[tn * 4 + 0]);
        const uint32_t k1b = __builtin_amdgcn_readfirstlane(keys_s[tn * 4 + 1]);
        hn = tf_normal(k1a, k1b, hnidx);
      }
    }
    if (tid == 0) {
      uint32_t* c = &cnt[((size_t)t * BB + b) * CNT_STRIDE];
      while (__hip_atomic_load(c, __ATOMIC_RELAXED, __HIP_MEMORY_SCOPE_AGENT) <
             (uint32_t)BPS)
        __builtin_amdgcn_s_sleep(1);
    }
    __syncthreads();

    // ---- P3: refresh h/a (w0-3) | hidden_list writes (w4-7) | x prefetch (w8-9) ----
    if (tid < NHID) {
      const float hv = __hip_atomic_load(&hpub[(par * BB + b) * NHID + tid],
                                         __ATOMIC_RELAXED, __HIP_MEMORY_SCOPE_AGENT);
      h_s[tid] = hv;
      a_s[tid] = tanhf(hv);
    } else if (tid < 512) {
      const int k = tid - 256;
      const float hv = __hip_atomic_load(&hpub[(par * BB + b) * NHID + k],
                                         __ATOMIC_RELAXED, __HIP_MEMORY_SCOPE_AGENT);
      out[((size_t)b * TT + t) * NHID + k] = hv;                        // hidden_list
      if (t == TT - 1)
        out[HID_LIST_SZ + OUT_LIST_SZ + (size_t)b * NHID + k] = hv;     // final hidden
    } else if (tid < 640) {
      const int k = tid - 512;
      if (t + 1 < TT) xt_s[k] = xin[((size_t)b * TT + t + 1) * NIN + k];
    }
    __syncthreads();
  }

  // ---- epilogue: output projection for t = 63 ----
  if (tid >= 512 && tid < 576) {
    float acc = 0.0f;
    #pragma unroll
    for (int q = 0; q < 4; ++q) {
      const float4 wv = wo[q];
      const float4 hv = *(const float4*)(h_s + sub * 16 + q * 4);
      acc = fmaf(wv.x, hv.x, acc); acc = fmaf(wv.y, hv.y, acc);
      acc = fmaf(wv.z, hv.z, acc); acc = fmaf(wv.w, hv.w, acc);
    }
    acc += __shfl_xor(acc, 8);
    acc += __shfl_xor(acc, 4);
    acc += __shfl_xor(acc, 2);
    acc += __shfl_xor(acc, 1);
    if (sub == 0)
      out[HID_LIST_SZ + ((size_t)b * TT + (TT - 1)) * NOUT + oo] = 20.0f * tanhf(acc);
  }
}

extern "C" void kernel_launch(void* const* d_in, const int* in_sizes, int n_in,
                              void* d_out, int out_size, void* d_ws, size_t ws_size,
                              hipStream_t stream) {
  (void)in_sizes; (void)n_in; (void)out_size; (void)ws_size;
  const float* x     = (const float*)d_in[0];
  const float* h0    = (const float*)d_in[1];
  // d_in[2] = length (always 64)
  const float* w_in  = (const float*)d_in[3];
  const float* w_hh  = (const float*)d_in[4];
  const float* b_hh  = (const float*)d_in[5];
  const float* w_out = (const float*)d_in[6];
  const float* alpha = (const float*)d_in[7];
  const float* beta  = (const float*)d_in[8];
  float* out = (float*)d_out;

  hipMemsetAsync((char*)d_ws + CNT_OFF, 0, CNT_BYTES, stream);  // arrive counters
  rnn_kernel<<<dim3(NBLK), dim3(NTHR), 0, stream>>>(
      x, h0, w_in, w_hh, b_hh, w_out, alpha, beta, out, (char*)d_ws);
}

// Round 4
// 1007.573 us; speedup vs baseline: 1.1867x; 1.0503x over previous
//
#include <hip/hip_runtime.h>
#include <stdint.h>

#define BB 64      // batch
#define TT 64      // time steps
#define NIN 128
#define NHID 256
#define NOUT 32
#define BPS 8                  // blocks per sample (j-sliced)
#define NBLK (BB * BPS)        // 512
#define NTHR 1024
#define JS 32                  // j-columns per block

#define SIG_NEU 0.05f
#define SIG_SYN 0.002f

// workspace layout (bytes)
#define FLAG_OFF    0
#define FLAG_STRIDE 32                                // u32s -> 128B per flag line
#define FLAG_BYTES  (BB * BPS * FLAG_STRIDE * 4)      // 64 KB, memset(0) per launch
#define HPUB_OFF    FLAG_BYTES                        // float[2][BB][NHID] = 128 KB

#define HID_LIST_SZ ((size_t)BB * TT * NHID)          // 1048576
#define OUT_LIST_SZ ((size_t)BB * TT * NOUT)          // 131072

__device__ __forceinline__ uint32_t rotl32(uint32_t v, int s) {
  return (v << s) | (v >> (32 - s));
}

// JAX threefry2x32 (5 groups of 4 rounds)
__device__ __forceinline__ void tf2x32(uint32_t k0, uint32_t k1, uint32_t x0, uint32_t x1,
                                       uint32_t& o0, uint32_t& o1) {
  const uint32_t k2 = k0 ^ k1 ^ 0x1BD11BDAu;
  x0 += k0; x1 += k1;
  x0 += x1; x1 = rotl32(x1,13); x1 ^= x0;
  x0 += x1; x1 = rotl32(x1,15); x1 ^= x0;
  x0 += x1; x1 = rotl32(x1,26); x1 ^= x0;
  x0 += x1; x1 = rotl32(x1, 6); x1 ^= x0;
  x0 += k1; x1 += k2 + 1u;
  x0 += x1; x1 = rotl32(x1,17); x1 ^= x0;
  x0 += x1; x1 = rotl32(x1,29); x1 ^= x0;
  x0 += x1; x1 = rotl32(x1,16); x1 ^= x0;
  x0 += x1; x1 = rotl32(x1,24); x1 ^= x0;
  x0 += k2; x1 += k0 + 2u;
  x0 += x1; x1 = rotl32(x1,13); x1 ^= x0;
  x0 += x1; x1 = rotl32(x1,15); x1 ^= x0;
  x0 += x1; x1 = rotl32(x1,26); x1 ^= x0;
  x0 += x1; x1 = rotl32(x1, 6); x1 ^= x0;
  x0 += k0; x1 += k1 + 3u;
  x0 += x1; x1 = rotl32(x1,17); x1 ^= x0;
  x0 += x1; x1 = rotl32(x1,29); x1 ^= x0;
  x0 += x1; x1 = rotl32(x1,16); x1 ^= x0;
  x0 += x1; x1 = rotl32(x1,24); x1 ^= x0;
  x0 += k1; x1 += k2 + 4u;
  x0 += x1; x1 = rotl32(x1,13); x1 ^= x0;
  x0 += x1; x1 = rotl32(x1,15); x1 ^= x0;
  x0 += x1; x1 = rotl32(x1,26); x1 ^= x0;
  x0 += x1; x1 = rotl32(x1, 6); x1 ^= x0;
  x0 += k2; x1 += k0 + 5u;
  o0 = x0; o1 = x1;
}

// partitionable random_bits(32) element idx -> N(0,1) exactly as jax.random.normal
__device__ __forceinline__ float tf_normal(uint32_t k0, uint32_t k1, uint32_t idx) {
  uint32_t o0, o1;
  tf2x32(k0, k1, 0u, idx, o0, o1);
  const uint32_t bits = o0 ^ o1;
  const float u = __uint_as_float((bits >> 9) | 0x3f800000u) - 1.0f;  // [0,1)
  float x = fmaf(u, 2.0f, -0.99999994f);                              // [-1+eps, 1)
  x = fmaxf(x, -0.99999994f);
  // XLA ErfInv f32 (Giles)
  const float w = -__logf(fmaf(-x, x, 1.0f));
  float p;
  if (w < 5.0f) {
    const float q = w - 2.5f;
    p = 2.81022636e-08f;
    p = fmaf(p, q, 3.43273939e-07f);
    p = fmaf(p, q, -3.5233877e-06f);
    p = fmaf(p, q, -4.39150654e-06f);
    p = fmaf(p, q, 0.00021858087f);
    p = fmaf(p, q, -0.00125372503f);
    p = fmaf(p, q, -0.00417768164f);
    p = fmaf(p, q, 0.246640727f);
    p = fmaf(p, q, 1.50140941f);
  } else {
    const float q = sqrtf(w) - 3.0f;
    p = -0.000200214257f;
    p = fmaf(p, q, 0.000100950558f);
    p = fmaf(p, q, 0.00134934322f);
    p = fmaf(p, q, -0.00367342844f);
    p = fmaf(p, q, 0.00573950773f);
    p = fmaf(p, q, -0.0076224613f);
    p = fmaf(p, q, 0.00943887047f);
    p = fmaf(p, q, 1.00167406f);
    p = fmaf(p, q, 2.83297682f);
  }
  return 1.41421356f * (p * x);  // sqrt(2)*erfinv
}

#define SPIN(slice, want)                                                         \
  do {                                                                            \
    uint32_t* fp_ = &flags[((b) * BPS + (slice)) * FLAG_STRIDE];                  \
    for (int it_ = 0; it_ < 300000; ++it_) {                                      \
      if (__hip_atomic_load(fp_, __ATOMIC_RELAXED, __HIP_MEMORY_SCOPE_AGENT) >=   \
          (uint32_t)(want)) break;                                                \
      __builtin_amdgcn_s_sleep(2);                                                \
    }                                                                             \
  } while (0)

__global__ __launch_bounds__(NTHR, 8) void rnn_kernel(
    const float* __restrict__ xin, const float* __restrict__ h0,
    const float* __restrict__ w_in, const float* __restrict__ w_hh,
    const float* __restrict__ b_hh, const float* __restrict__ w_out,
    const float* __restrict__ alpha, const float* __restrict__ beta,
    float* __restrict__ out, char* __restrict__ ws)
{
  __shared__ __align__(16) float wos[4 * 260];   // w_out slice, +4 pad per row
  __shared__ __align__(16) float h_s[NHID];
  __shared__ __align__(16) float a_s[NHID];
  __shared__ __align__(16) float xt_s[NIN];
  __shared__ float stat_s[JS];
  __shared__ float djact_s[JS];
  __shared__ uint32_t keys_s[TT * 4];

  const int tid = threadIdx.x;
  const int blk = blockIdx.x;
  const int b   = blk & 63;      // sample; siblings share blk%8 -> same XCD class
  const int s   = blk >> 6;      // 0..7 j-slice index

  uint32_t* flags = (uint32_t*)(ws + FLAG_OFF);
  float*    hpub  = (float*)(ws + HPUB_OFF);

  // ---------------- init ----------------
  if (tid < TT) {
    uint32_t ka, kb, t0, t1;
    tf2x32(0u, 42u, 0u, (uint32_t)tid, ka, kb);   // keys[t] = split(key(42),64)[t]
    tf2x32(ka, kb, 0u, 0u, t0, t1);               // k1 (neural)
    keys_s[tid * 4 + 0] = t0; keys_s[tid * 4 + 1] = t1;
    tf2x32(ka, kb, 0u, 1u, t0, t1);               // k2 (synaptic)
    keys_s[tid * 4 + 2] = t0; keys_s[tid * 4 + 3] = t1;
  }
  if (tid < NHID) {
    const float hv = h0[b * NHID + tid];
    h_s[tid] = hv;
    a_s[tid] = tanhf(hv);
  }
  {
    const int r = tid >> 8, c = tid & 255;        // load w_out slice to LDS
    wos[r * 260 + c] = w_out[(s * 4 + r) * NHID + c];
  }

  // shared index: c5 = dj column (local) == GEMV row (local)
  const int u  = tid & 31;
  const int c5 = tid >> 5;           // 0..31
  const int jg = s * JS + c5;        // global j / GEMV row
  const float bj  = beta[jg];
  const float sbj = SIG_SYN * sqrtf(bj);
  const uint32_t idxb = ((uint32_t)b << 16) | ((uint32_t)u << 8) | (uint32_t)jg;

  // loop-invariant GEMV weights in registers (12 VGPR)
  const float4 whr0 = *(const float4*)(w_hh + (size_t)jg * NHID + 0 * 128 + u * 4);
  const float4 whr1 = *(const float4*)(w_hh + (size_t)jg * NHID + 1 * 128 + u * 4);
  const float4 winr = *(const float4*)(w_in + (size_t)jg * NIN + u * 4);
  const float bias  = b_hh[jg];

  // h-update consts (tid<32)
  float r_al = 0.f, r_om = 0.f, r_ns = 0.f;
  uint32_t hnidx = 0;
  if (tid < JS) {
    r_al = alpha[s * JS + tid];
    r_om = 1.0f - r_al;
    r_ns = SIG_NEU * sqrtf(r_al);
    hnidx = (uint32_t)(b * NHID + s * JS + tid);
  }

  float d[8];
  #pragma unroll
  for (int r = 0; r < 8; ++r) d[r] = 0.0f;
  float n[8];
  float hn = 0.0f;

  __syncthreads();

  // -------- prologue: RNG for t=0, x_0 --------
  {
    const uint32_t k2a = __builtin_amdgcn_readfirstlane(keys_s[2]);
    const uint32_t k2b = __builtin_amdgcn_readfirstlane(keys_s[3]);
    #pragma unroll
    for (int r = 0; r < 8; ++r)
      n[r] = tf_normal(k2a, k2b, idxb + ((uint32_t)r << 13));
    if (tid < JS) {
      const uint32_t k1a = __builtin_amdgcn_readfirstlane(keys_s[0]);
      const uint32_t k1b = __builtin_amdgcn_readfirstlane(keys_s[1]);
      hn = tf_normal(k1a, k1b, hnidx);
    }
    if (tid < NIN) xt_s[tid] = xin[((size_t)b * TT) * NIN + tid];
  }
  __syncthreads();

  const int wv = tid >> 6;     // wave id 0..15
  const int ln = tid & 63;

  for (int t = 0; t < TT; ++t) {
    const int par = t & 1;

    // ================ P1: dj + GEMV + outproj(t-1) ================
    const float aj = a_s[jg];
    float pd = 0.0f;
    #pragma unroll
    for (int r = 0; r < 8; ++r) {
      const float ai = a_s[u + 32 * r];
      pd = fmaf(ai, d[r], pd);                         // uses OLD dj
      d[r] = fmaf(bj, fmaf(n[r], sbj, -ai * aj), d[r]);
    }
    pd += __shfl_xor(pd, 1);
    pd += __shfl_xor(pd, 2);
    pd += __shfl_xor(pd, 4);
    pd += __shfl_xor(pd, 8);
    pd += __shfl_xor(pd, 16);
    if (u == 0) djact_s[c5] = pd;

    {  // GEMV: all 1024 threads, 32 lanes per row, weights in regs
      float acc = 0.0f;
      const float4 x4 = *((const float4*)xt_s + u);
      acc = fmaf(winr.x, x4.x, acc); acc = fmaf(winr.y, x4.y, acc);
      acc = fmaf(winr.z, x4.z, acc); acc = fmaf(winr.w, x4.w, acc);
      const float4 a0 = *((const float4*)a_s + u);
      acc = fmaf(whr0.x, a0.x, acc); acc = fmaf(whr0.y, a0.y, acc);
      acc = fmaf(whr0.z, a0.z, acc); acc = fmaf(whr0.w, a0.w, acc);
      const float4 a1 = *((const float4*)a_s + 32 + u);
      acc = fmaf(whr1.x, a1.x, acc); acc = fmaf(whr1.y, a1.y, acc);
      acc = fmaf(whr1.z, a1.z, acc); acc = fmaf(whr1.w, a1.w, acc);
      acc += __shfl_xor(acc, 1);
      acc += __shfl_xor(acc, 2);
      acc += __shfl_xor(acc, 4);
      acc += __shfl_xor(acc, 8);
      acc += __shfl_xor(acc, 16);
      if (u == 0) stat_s[c5] = acc + bias;
    }

    if (wv == 8 && t > 0) {   // output projection for t-1 (h_s = h(t-1))
      const int o = ln >> 4, sub = ln & 15;
      float acc = 0.0f;
      #pragma unroll
      for (int q = 0; q < 4; ++q) {
        const float4 wvv = *(const float4*)(wos + o * 260 + q * 64 + sub * 4);
        const float4 hv  = *(const float4*)(h_s + q * 64 + sub * 4);
        acc = fmaf(wvv.x, hv.x, acc); acc = fmaf(wvv.y, hv.y, acc);
        acc = fmaf(wvv.z, hv.z, acc); acc = fmaf(wvv.w, hv.w, acc);
      }
      acc += __shfl_xor(acc, 8);
      acc += __shfl_xor(acc, 4);
      acc += __shfl_xor(acc, 2);
      acc += __shfl_xor(acc, 1);
      if (sub == 0)
        out[HID_LIST_SZ + ((size_t)b * TT + (t - 1)) * NOUT + s * 4 + o] =
            20.0f * tanhf(acc);
    }
    __syncthreads();

    // ================ P2: h-update + publish, then RNG(t+1) ================
    if (tid < JS) {
      const float tmp  = stat_s[tid] + djact_s[tid];
      const float hnew = fmaf(r_al, tmp, r_om * h_s[s * JS + tid]) + hn * r_ns;
      __hip_atomic_store(&hpub[(par * BB + b) * NHID + s * JS + tid], hnew,
                         __ATOMIC_RELAXED, __HIP_MEMORY_SCOPE_AGENT);
    }
    if (tid == 0) {
      asm volatile("s_waitcnt vmcnt(0)" ::: "memory");   // h-slice visible first
      __hip_atomic_store(&flags[(b * BPS + s) * FLAG_STRIDE], (uint32_t)(t + 1),
                         __ATOMIC_RELAXED, __HIP_MEMORY_SCOPE_AGENT);
    }
    if (t + 1 < TT) {   // RNG for next step — hides the flag/publish latency
      const uint32_t k2a = __builtin_amdgcn_readfirstlane(keys_s[(t + 1) * 4 + 2]);
      const uint32_t k2b = __builtin_amdgcn_readfirstlane(keys_s[(t + 1) * 4 + 3]);
      #pragma unroll
      for (int r = 0; r < 8; ++r)
        n[r] = tf_normal(k2a, k2b, idxb + ((uint32_t)r << 13));
      if (tid < JS) {
        const uint32_t k1a = __builtin_amdgcn_readfirstlane(keys_s[(t + 1) * 4 + 0]);
        const uint32_t k1b = __builtin_amdgcn_readfirstlane(keys_s[(t + 1) * 4 + 1]);
        hn = tf_normal(k1a, k1b, hnidx);
      }
    }

    // ================ P3: poll flags, pull h(t), side jobs ================
    if (wv < 8) {
      if (ln == 0) SPIN(wv, t + 1);
      asm volatile("" ::: "memory");
      if (ln < JS) {
        const float hv = __hip_atomic_load(&hpub[(par * BB + b) * NHID + wv * JS + ln],
                                           __ATOMIC_RELAXED, __HIP_MEMORY_SCOPE_AGENT);
        h_s[wv * JS + ln] = hv;
        a_s[wv * JS + ln] = tanhf(hv);
      }
    } else if (wv < 12) {
      if (s == 0) {   // hidden_list (deduped: only s==0 writes)
        const int k = (wv - 8) * 64 + ln;           // 0..255
        if (ln == 0)       SPIN(2 * (wv - 8), t + 1);
        else if (ln == 32) SPIN(2 * (wv - 8) + 1, t + 1);
        asm volatile("" ::: "memory");
        const float hv = __hip_atomic_load(&hpub[(par * BB + b) * NHID + k],
                                           __ATOMIC_RELAXED, __HIP_MEMORY_SCOPE_AGENT);
        out[((size_t)b * TT + t) * NHID + k] = hv;
        if (t == TT - 1)
          out[HID_LIST_SZ + OUT_LIST_SZ + (size_t)b * NHID + k] = hv;
      }
    } else if (wv < 14) {
      const int k = (wv - 12) * 64 + ln;            // 0..127: x prefetch
      if (t + 1 < TT) xt_s[k] = xin[((size_t)b * TT + t + 1) * NIN + k];
    }
    __syncthreads();
  }

  // ---- epilogue: output projection for t = 63 (h_s = h(63)) ----
  if (wv == 8) {
    const int o = ln >> 4, sub = ln & 15;
    float acc = 0.0f;
    #pragma unroll
    for (int q = 0; q < 4; ++q) {
      const float4 wvv = *(const float4*)(wos + o * 260 + q * 64 + sub * 4);
      const float4 hv  = *(const float4*)(h_s + q * 64 + sub * 4);
      acc = fmaf(wvv.x, hv.x, acc); acc = fmaf(wvv.y, hv.y, acc);
      acc = fmaf(wvv.z, hv.z, acc); acc = fmaf(wvv.w, hv.w, acc);
    }
    acc += __shfl_xor(acc, 8);
    acc += __shfl_xor(acc, 4);
    acc += __shfl_xor(acc, 2);
    acc += __shfl_xor(acc, 1);
    if (sub == 0)
      out[HID_LIST_SZ + ((size_t)b * TT + (TT - 1)) * NOUT + s * 4 + o] =
          20.0f * tanhf(acc);
  }
}

extern "C" void kernel_launch(void* const* d_in, const int* in_sizes, int n_in,
                              void* d_out, int out_size, void* d_ws, size_t ws_size,
                              hipStream_t stream) {
  (void)in_sizes; (void)n_in; (void)out_size; (void)ws_size;
  const float* x     = (const float*)d_in[0];
  const float* h0    = (const float*)d_in[1];
  // d_in[2] = length (always 64)
  const float* w_in  = (const float*)d_in[3];
  const float* w_hh  = (const float*)d_in[4];
  const float* b_hh  = (const float*)d_in[5];
  const float* w_out = (const float*)d_in[6];
  const float* alpha = (const float*)d_in[7];
  const float* beta  = (const float*)d_in[8];
  float* out = (float*)d_out;

  hipMemsetAsync((char*)d_ws + FLAG_OFF, 0, FLAG_BYTES, stream);  // flag slots
  rnn_kernel<<<dim3(NBLK), dim3(NTHR), 0, stream>>>(
      x, h0, w_in, w_hh, b_hh, w_out, alpha, beta, out, (char*)d_ws);
}